// Round 8
// baseline (176.542 us; speedup 1.0000x reference)
//
#include <hip/hip_runtime.h>

#define NEGF -1000000000.0f
#define LOG2E 1.4426950408889634f
#define LN2 0.6931471805599453f

constexpr int Bn = 64;
constexpr int Tn = 1000;
constexpr int Un = 250;

// gfx950-native base-2 transcendentals: v_exp_f32 is 2^x, v_log_f32 is log2(x)
__device__ __forceinline__ float exp2fast(float x) { return __builtin_amdgcn_exp2f(x); }
__device__ __forceinline__ float log2fast(float x) { return __builtin_amdgcn_logf(x); }

// ---------------------------------------------------------------------------
// DPP cross-lane ops (validated on-device rounds 6-7).
//   wave_shr:1 (0x138) + bound_ctrl=1: lane i <- lane i-1, lane 0 <- 0.
//   Reductions: row_shr 1/2/4/8 + row_bcast:15/31, result in lane 63.
// ---------------------------------------------------------------------------
template <int CTRL>
__device__ __forceinline__ float dppmov(float x) {
    return __int_as_float(__builtin_amdgcn_update_dpp(
        0, __float_as_int(x), CTRL, 0xf, 0xf, true));
}
__device__ __forceinline__ float dpp_wave_shr1(float x) { return dppmov<0x138>(x); }

__device__ __forceinline__ float wave_red_max(float x) {  // = max(max_x, 0)
    x = fmaxf(x, dppmov<0x111>(x));
    x = fmaxf(x, dppmov<0x112>(x));
    x = fmaxf(x, dppmov<0x114>(x));
    x = fmaxf(x, dppmov<0x118>(x));
    x = fmaxf(x, dppmov<0x142>(x));
    x = fmaxf(x, dppmov<0x143>(x));
    return __int_as_float(__builtin_amdgcn_readlane(__float_as_int(x), 63));
}
__device__ __forceinline__ float wave_red_sum(float x) {
    x += dppmov<0x111>(x);
    x += dppmov<0x112>(x);
    x += dppmov<0x114>(x);
    x += dppmov<0x118>(x);
    x += dppmov<0x142>(x);
    x += dppmov<0x143>(x);
    return __int_as_float(__builtin_amdgcn_readlane(__float_as_int(x), 63));
}

// ---------------------------------------------------------------------------
// Kernel 1: per-row log-softmax denominator, in log2 units (verified r7).
// 4 rows per wave, 4 waves per block -> 1000 workgroups. Also zeroes d_out.
// ---------------------------------------------------------------------------
__global__ void __launch_bounds__(256) zrow_kernel(const float* __restrict__ attn,
                                                   const int* __restrict__ text_lens,
                                                   float* __restrict__ Z2,
                                                   float* __restrict__ out) {
    if (blockIdx.x == 0 && threadIdx.x == 0) *out = 0.0f;
    int wid = threadIdx.x >> 6;
    int lane = threadIdx.x & 63;
    int row0 = (blockIdx.x * 4 + wid) * 4;     // 4 consecutive rows per wave

    float v[4][4];
    int Ls[4];
#pragma unroll
    for (int r = 0; r < 4; ++r) {
        int row = row0 + r;
        Ls[r] = text_lens[row / Tn];
        const float* p = attn + (size_t)row * Un;
#pragma unroll
        for (int i = 0; i < 4; ++i) {
            int u = lane + 64 * i;
            v[r][i] = (u < Un) ? p[u] : 0.0f;  // in-bounds read; mask vs L below
        }
    }
#pragma unroll
    for (int r = 0; r < 4; ++r) {
        int L = Ls[r];
        float m = (lane == 0) ? -LOG2E : NEGF;
#pragma unroll
        for (int i = 0; i < 4; ++i) {
            int u = lane + 64 * i;
            v[r][i] = (u < L) ? v[r][i] * LOG2E : NEGF;
            m = fmaxf(m, v[r][i]);
        }
        m = wave_red_max(m);                   // wave-uniform; = max(max, 0), exact shift
        float s = (lane == 0) ? exp2fast(-LOG2E - m) : 0.0f;
#pragma unroll
        for (int i = 0; i < 4; ++i) s += exp2fast(v[r][i] - m);  // NEGF-m -> 0
        s = wave_red_sum(s);
        if (lane == 0) Z2[row0 + r] = m + log2fast(s);
    }
}

// ---------------------------------------------------------------------------
// Kernel 2: CTC forward recursion in the LINEAR domain, one wave per batch.
// State s = lane*8 + j. Power-of-2 renorm every 8 steps; Esum accumulates
// the stripped exponent (log2 units).
//   odd  s: a' = (a[s]+a[s-1]+a[s-2]) * e^{logit[col]}
//   even s: a' = (a[s]+a[s-1]) * e^{-1}
// Masking folded into the exp2 input (fma bias -1e6 -> q=0).
// Cross-lane alpha[8*lane-1]: DPP wave_shr:1 on old a7 (1 VALU op).
//
// r8 changes vs r7:
//  * ONE s_waitcnt vmcnt(16) per 8-step group (waits for the oldest 16 of 32
//    outstanding = exactly the 8 rows about to be consumed) instead of a
//    per-step waitcnt — m135: each executed waitcnt costs substantial fixed
//    cycles even when satisfied.
//  * Renorm split BEGIN/APPLY across a step: the recursion is linear in
//    alpha, so scaling after step k == scaling before step k. The 6-stage
//    DPP max chain (BEGIN, after steps 7/15) interleaves with the next
//    step's arithmetic; APPLY (after steps 8/0') is 8 muls + SALU.
// ---------------------------------------------------------------------------
typedef float v2f __attribute__((ext_vector_type(2)));

#define CTC_REFILL(J, T)                                                      \
    {                                                                         \
        int tl_ = (T) <= last ? (T) : last;                                   \
        const char* rowp_ = pbase + (size_t)tl_ * 1000;                       \
        asm volatile("global_load_dwordx2 %0, %1, %2"                         \
                     : "=v"(lo[J]) : "v"(voff_lo), "s"(rowp_));               \
        asm volatile("global_load_dwordx2 %0, %1, %2"                         \
                     : "=v"(hi[J]) : "v"(voff_hi), "s"(rowp_));               \
    }

// wait for the 8-row group starting at slot A (A = 0 or 8); ties the group's
// buffer registers as in-outs so consuming FMAs stay ordered after the wait.
#define CTC_WAITGRP(A)                                                        \
    asm volatile("s_waitcnt vmcnt(16)"                                        \
                 : "+v"(lo[A + 0]), "+v"(hi[A + 0]), "+v"(lo[A + 1]),         \
                   "+v"(hi[A + 1]), "+v"(lo[A + 2]), "+v"(hi[A + 2]),         \
                   "+v"(lo[A + 3]), "+v"(hi[A + 3]), "+v"(lo[A + 4]),         \
                   "+v"(hi[A + 4]), "+v"(lo[A + 5]), "+v"(hi[A + 5]),         \
                   "+v"(lo[A + 6]), "+v"(hi[A + 6]), "+v"(lo[A + 7]),         \
                   "+v"(hi[A + 7]));

#define CTC_STEP_BODY(J)                                                      \
    {                                                                         \
        float q0 = exp2fast(__builtin_fmaf(lo[J].x, LOG2E, bias0));           \
        float q1 = exp2fast(__builtin_fmaf(lo[J].y, LOG2E, bias1));           \
        float q2 = exp2fast(__builtin_fmaf(hi[J].x, LOG2E, bias2));           \
        float q3 = exp2fast(__builtin_fmaf(hi[J].y, LOG2E, bias3));           \
        float p7 = dpp_wave_shr1(a7); /* old a7 of lane-1; lane0 -> 0 */      \
        float s65 = a6 + a5, s43 = a4 + a3, s21 = a2 + a1, s0p = a0 + p7;     \
        a7 = (a7 + s65) * q3;  a6 = s65 * QB;                                 \
        a5 = (a5 + s43) * q2;  a4 = s43 * QB;                                 \
        a3 = (a3 + s21) * q1;  a2 = s21 * QB;                                 \
        a1 = (a1 + s0p) * q0;  a0 = s0p * QB;                                 \
    }

#define CTC_STEP_W0(J)                                                        \
    {                                                                         \
        asm volatile("s_waitcnt vmcnt(0)" : "+v"(lo[J]), "+v"(hi[J]));        \
        CTC_STEP_BODY(J)                                                      \
    }

#define RENORM_BEGIN()                                                        \
    {                                                                         \
        float m_ = fmaxf(fmaxf(fmaxf(a0, a1), fmaxf(a2, a3)),                 \
                         fmaxf(fmaxf(a4, a5), fmaxf(a6, a7)));                \
        m_ = fmaxf(m_, dppmov<0x111>(m_));                                    \
        m_ = fmaxf(m_, dppmov<0x112>(m_));                                    \
        m_ = fmaxf(m_, dppmov<0x114>(m_));                                    \
        m_ = fmaxf(m_, dppmov<0x118>(m_));                                    \
        m_ = fmaxf(m_, dppmov<0x142>(m_));                                    \
        m_ = fmaxf(m_, dppmov<0x143>(m_));                                    \
        mx = m_; /* lane 63 holds the wave max (alphas >= 0, > 0) */          \
    }

#define RENORM_APPLY()                                                        \
    {                                                                         \
        unsigned u_ = (unsigned)__builtin_amdgcn_readlane(__float_as_int(mx), 63); \
        int e_ = (int)((u_ >> 23) & 255) - 127;                               \
        float scale_ = __uint_as_float((unsigned)(127 - e_) << 23);           \
        a0 *= scale_; a1 *= scale_; a2 *= scale_; a3 *= scale_;               \
        a4 *= scale_; a5 *= scale_; a6 *= scale_; a7 *= scale_;               \
        Esum += (float)e_;                                                    \
    }

__global__ void __launch_bounds__(64, 1) ctc_kernel(const float* __restrict__ attn,
                                                    const int* __restrict__ text_lens,
                                                    const int* __restrict__ mel_lens,
                                                    const float* __restrict__ Z2,
                                                    float* __restrict__ out) {
    int b = blockIdx.x;
    int lane = threadIdx.x;
    int L = text_lens[b];
    int n_t = mel_lens[b];
    const char* pbase = (const char*)(attn + (size_t)b * Tn * Un);

    // per-lane safe byte offsets within a 1000B row (8B aligned, never OOB):
    // lane62 hi aliases lo (its cols 250/251 always masked since L<=250),
    // lane63 reads col 0 (all its states masked).
    int voff_lo = lane * 16, voff_hi = lane * 16 + 8;
    if (lane == 62) { voff_lo = 992; voff_hi = 992; }
    if (lane == 63) { voff_lo = 0;   voff_hi = 0;   }
    int c0 = lane * 4;
    float bias0 = (c0 + 0 < L) ? 0.0f : -1000000.0f;
    float bias1 = (c0 + 1 < L) ? 0.0f : -1000000.0f;
    float bias2 = (c0 + 2 < L) ? 0.0f : -1000000.0f;
    float bias3 = (c0 + 3 < L) ? 0.0f : -1000000.0f;

    const float QB = 0.36787944117144233f;  // e^-1 (blank, unnormalized)
    float a0 = (lane == 0) ? 1.0f : 0.0f;
    float a1 = 0.0f, a2 = 0.0f, a3 = 0.0f, a4 = 0.0f, a5 = 0.0f, a6 = 0.0f, a7 = 0.0f;
    float Esum = 0.0f;  // accumulated renorm exponent, log2 units
    float mx = 1.0f;    // pending renorm max (e=0 -> first APPLY is a no-op)

    v2f lo[16], hi[16];
    int last = n_t - 1;

    // prologue: 16 rows = 32 loads in flight
#pragma unroll
    for (int j = 0; j < 16; ++j) CTC_REFILL(j, j);

    int full = n_t & ~15;
    int t = 0;
    for (; t < full; t += 16) {
        CTC_WAITGRP(0);
        CTC_STEP_BODY(0);  CTC_REFILL(0, t + 16);  RENORM_APPLY();
        CTC_STEP_BODY(1);  CTC_REFILL(1, t + 17);
        CTC_STEP_BODY(2);  CTC_REFILL(2, t + 18);
        CTC_STEP_BODY(3);  CTC_REFILL(3, t + 19);
        CTC_STEP_BODY(4);  CTC_REFILL(4, t + 20);
        CTC_STEP_BODY(5);  CTC_REFILL(5, t + 21);
        CTC_STEP_BODY(6);  CTC_REFILL(6, t + 22);
        CTC_STEP_BODY(7);  CTC_REFILL(7, t + 23);  RENORM_BEGIN();
        CTC_WAITGRP(8);
        CTC_STEP_BODY(8);  CTC_REFILL(8, t + 24);  RENORM_APPLY();
        CTC_STEP_BODY(9);  CTC_REFILL(9, t + 25);
        CTC_STEP_BODY(10); CTC_REFILL(10, t + 26);
        CTC_STEP_BODY(11); CTC_REFILL(11, t + 27);
        CTC_STEP_BODY(12); CTC_REFILL(12, t + 28);
        CTC_STEP_BODY(13); CTC_REFILL(13, t + 29);
        CTC_STEP_BODY(14); CTC_REFILL(14, t + 30);
        CTC_STEP_BODY(15); CTC_REFILL(15, t + 31); RENORM_BEGIN();
        // pending mx applied after the next executed step (loop or tail)
    }
    // tail (<= 15 steps); slots j hold rows full+j. First wait drains all,
    // subsequent vmcnt(0) are free. Pending RENORM applied after step 0;
    // mid-tail full renorm after step 7 caps any unrenormed run at 8 steps.
    if (t + 0 < n_t) { CTC_STEP_W0(0); RENORM_APPLY(); }
    if (t + 1 < n_t) CTC_STEP_W0(1);
    if (t + 2 < n_t) CTC_STEP_W0(2);
    if (t + 3 < n_t) CTC_STEP_W0(3);
    if (t + 4 < n_t) CTC_STEP_W0(4);
    if (t + 5 < n_t) CTC_STEP_W0(5);
    if (t + 6 < n_t) CTC_STEP_W0(6);
    if (t + 7 < n_t) CTC_STEP_W0(7);
    if (t + 8 < n_t) { RENORM_BEGIN(); RENORM_APPLY(); CTC_STEP_W0(8); }
    if (t + 9 < n_t) CTC_STEP_W0(9);
    if (t + 10 < n_t) CTC_STEP_W0(10);
    if (t + 11 < n_t) CTC_STEP_W0(11);
    if (t + 12 < n_t) CTC_STEP_W0(12);
    if (t + 13 < n_t) CTC_STEP_W0(13);
    if (t + 14 < n_t) CTC_STEP_W0(14);
    asm volatile("s_waitcnt vmcnt(0)" ::: "memory");  // drain stale prefetches

    __shared__ float sal[512];
    sal[lane * 8 + 0] = a0;
    sal[lane * 8 + 1] = a1;
    sal[lane * 8 + 2] = a2;
    sal[lane * 8 + 3] = a3;
    sal[lane * 8 + 4] = a4;
    sal[lane * 8 + 5] = a5;
    sal[lane * 8 + 6] = a6;
    sal[lane * 8 + 7] = a7;
    __syncthreads();

    // sum of log-softmax denominators over t < n_t (log2 units)
    float zs = 0.0f;
    for (int i = lane; i < n_t; i += 64) zs += Z2[b * Tn + i];
    zs = wave_red_sum(zs);

    if (lane == 0) {
        float ssum = sal[2 * L] + sal[2 * L - 1];
        float fin = (log2fast(ssum) + Esum - zs) * LN2;
        float loss = (ssum <= 0.0f) ? 0.0f : (-fin / (float)L);
        atomicAdd(out, loss * (1.0f / (float)Bn));
    }
}

extern "C" void kernel_launch(void* const* d_in, const int* in_sizes, int n_in,
                              void* d_out, int out_size, void* d_ws, size_t ws_size,
                              hipStream_t stream) {
    const float* attn = (const float*)d_in[0];
    const int* text_lens = (const int*)d_in[1];
    const int* mel_lens = (const int*)d_in[2];
    float* out = (float*)d_out;
    float* Z2 = (float*)d_ws;  // Bn*Tn floats = 256 KB

    // zrow also zeroes d_out (stream-ordered before ctc_kernel's atomicAdd)
    zrow_kernel<<<Bn * Tn / 16, 256, 0, stream>>>(attn, text_lens, Z2, out);
    ctc_kernel<<<Bn, 64, 0, stream>>>(attn, text_lens, mel_lens, Z2, out);
}